// Round 9
// baseline (384.340 us; speedup 1.0000x reference)
//
#include <hip/hip_runtime.h>

constexpr int FIN = 512;
constexpr int HID = 16;
constexpr int NC  = 7;

// ---------------- CSR build ----------------

__global__ void k_bsum(const int* __restrict__ cnt, int* __restrict__ bsum, int N) {
    int i = blockIdx.x * 256 + threadIdx.x;
    int v = (i < N) ? cnt[i] : 0;
#pragma unroll
    for (int o = 1; o < 64; o <<= 1) v += __shfl_xor(v, o);
    __shared__ int ws_[4];
    if ((threadIdx.x & 63) == 0) ws_[threadIdx.x >> 6] = v;
    __syncthreads();
    if (threadIdx.x == 0) bsum[blockIdx.x] = ws_[0] + ws_[1] + ws_[2] + ws_[3];
}

__global__ void k_scanb(const int* __restrict__ bsum, int* __restrict__ boff, int nb) {
    __shared__ int s[1024];
    int t = threadIdx.x;
    int mine = (t < nb) ? bsum[t] : 0;
    s[t] = mine;
    __syncthreads();
    for (int o = 1; o < 1024; o <<= 1) {
        int v = (t >= o) ? s[t - o] : 0;
        __syncthreads();
        s[t] += v;
        __syncthreads();
    }
    if (t < nb) boff[t] = s[t] - mine;  // exclusive
}

__global__ void k_rowptr(const int* __restrict__ cnt, const int* __restrict__ boff,
                         int* __restrict__ rowptr, int* __restrict__ cursor,
                         float* __restrict__ dinv, int N, int E) {
    int i = blockIdx.x * 256 + threadIdx.x;
    int v = (i < N) ? cnt[i] : 0;
    int lane = threadIdx.x & 63, w = threadIdx.x >> 6;
    int xs = v;
#pragma unroll
    for (int o = 1; o < 64; o <<= 1) {
        int y = __shfl_up(xs, o);
        if (lane >= o) xs += y;
    }
    __shared__ int wsum[4];
    if (lane == 63) wsum[w] = xs;
    __syncthreads();
    int woff = 0;
    for (int k = 0; k < w; ++k) woff += wsum[k];
    if (i < N) {
        int rp = boff[blockIdx.x] + woff + xs - v;
        rowptr[i] = rp;
        cursor[i] = rp;
        dinv[i] = rsqrtf((float)v + 1.0f);
    }
    if (i == N) rowptr[N] = E;
}

// ---------------- fused: t0 = x @ W0 (unscaled)  +  hist ----------------
// xw0 blocks: 4 waves x 64 rows; wave w streams cols [128w,128w+128).
// Per lane: 512B contiguous, 8 batches of 4 consecutive float4 (one full
// 64B line per batch -> no over-fetch). Cross-wave k-split reduced via
// padded-LDS epilogue. Grid gives 24 waves/CU; launch_bounds(256,4) caps
// VGPR at 128 so >=16 waves/CU stay resident -> BW = waves x outstanding.

__global__ void __launch_bounds__(256, 4) k_xw0_hist(
    const float* __restrict__ x, const float* __restrict__ W0,
    float* __restrict__ t0, int N, int nbx,
    const int* __restrict__ dst, int* __restrict__ cnt, int E) {
    __shared__ float red[256 * 17];  // 17408 B

    if ((int)blockIdx.x >= nbx) {  // -------- hist blocks --------
        int e = (blockIdx.x - nbx) * 256 + threadIdx.x;
        if (e < E) atomicAdd(&cnt[dst[e]], 1);
        return;
    }

    const int tid = threadIdx.x;
    const int w = tid >> 6;       // wave id = k-split 0..3
    const int lane = tid & 63;
    int row = blockIdx.x * 64 + lane;
    int r = row < N ? row : N - 1;
    const float4* xr = (const float4*)(x + (size_t)r * FIN + w * 128);

    float acc[HID];
#pragma unroll
    for (int j = 0; j < HID; ++j) acc[j] = 0.f;

    float4 A[4], B[4];
#pragma unroll
    for (int i = 0; i < 4; ++i) A[i] = xr[i];  // batch 0 (one 64B line/lane)

#pragma unroll
    for (int b = 0; b < 8; ++b) {  // 8 batches x 16 k
        const float4* cur = (b & 1) ? B : A;
        float4* nxt = (b & 1) ? A : B;
        if (b + 1 < 8) {
#pragma unroll
            for (int i = 0; i < 4; ++i) nxt[i] = xr[(b + 1) * 4 + i];
        }
        const float* wk = W0 + (size_t)(w * 128 + b * 16) * HID;  // wave-uniform
#pragma unroll
        for (int i = 0; i < 4; ++i) {
            float4 xv = cur[i];
            const float* w_ = wk + i * 4 * HID;
#pragma unroll
            for (int j = 0; j < HID; ++j) {
                acc[j] = fmaf(xv.x, w_[j], acc[j]);
                acc[j] = fmaf(xv.y, w_[HID + j], acc[j]);
                acc[j] = fmaf(xv.z, w_[2 * HID + j], acc[j]);
                acc[j] = fmaf(xv.w, w_[3 * HID + j], acc[j]);
            }
        }
    }

    // cross-wave k-split reduction via padded LDS (stride 17: conflict-free)
#pragma unroll
    for (int j = 0; j < HID; ++j) red[tid * 17 + j] = acc[j];
    __syncthreads();
    if (tid < 64) {
        if (row < N) {
            float4* gp = (float4*)(t0 + (size_t)row * HID);
#pragma unroll
            for (int q = 0; q < 4; ++q) {
                float4 v;
#pragma unroll
                for (int u = 0; u < 4; ++u) {
                    int j = q * 4 + u;
                    (&v.x)[u] = red[tid * 17 + j] + red[(tid + 64) * 17 + j] +
                                red[(tid + 128) * 17 + j] + red[(tid + 192) * 17 + j];
                }
                gp[q] = v;
            }
        }
    }
}

// ---------------- fused: CSR fill + g0 *= dinv (in place) ----------------

__global__ void k_fill_scale(const int* __restrict__ src, const int* __restrict__ dst,
                             int* __restrict__ cursor, int* __restrict__ esrc, int E,
                             int nbf, float4* __restrict__ g4,
                             const float* __restrict__ dinv, int n4) {
    if ((int)blockIdx.x < nbf) {  // -------- fill blocks --------
        int e = blockIdx.x * 256 + threadIdx.x;
        if (e < E) {
            int p = atomicAdd(&cursor[dst[e]], 1);
            esrc[p] = src[e];
        }
        return;
    }
    int t = (blockIdx.x - nbf) * 256 + threadIdx.x;  // -------- scale blocks --------
    if (t < n4) {
        float dv = dinv[t >> 2];
        float4 v = g4[t];
        v.x *= dv; v.y *= dv; v.z *= dv; v.w *= dv;
        g4[t] = v;
    }
}

// ---------------- pull aggregation (wave per dst row, batched gathers) -------

__global__ void k_pull0(const int* __restrict__ rowptr, const int* __restrict__ esrc,
                        const float* __restrict__ g0, float* __restrict__ s0, int N) {
    int wid = (blockIdx.x * 256 + threadIdx.x) >> 6;
    if (wid >= N) return;
    int lane = threadIdx.x & 63;
    int grp = lane >> 4, j = lane & 15;
    int e0 = rowptr[wid], e1 = rowptr[wid + 1];
    float acc = 0.f;
    for (int base = e0; base < e1; base += 16) {
        int p = base + (lane & 15);
        int v = (p < e1) ? esrc[p] : 0;
#pragma unroll
        for (int u = 0; u < 4; ++u) {
            int k = grp + 4 * u;
            int idx = __shfl(v, k);
            if (base + k < e1) acc += g0[(size_t)idx * HID + j];
        }
    }
    acc += __shfl_xor(acc, 16);
    acc += __shfl_xor(acc, 32);
    if (grp == 0)
        s0[(size_t)wid * HID + j] = acc + g0[(size_t)wid * HID + j];
}

__global__ void k_h1w1(const float* __restrict__ s0, const float* __restrict__ dinv,
                       const float* __restrict__ b0, const float* __restrict__ W1,
                       float* __restrict__ g1, int N) {
    int i = blockIdx.x * 256 + threadIdx.x;
    if (i >= N) return;
    float dv = dinv[i];
    const float4* sp = (const float4*)(s0 + (size_t)i * HID);
    float4 a = sp[0], b = sp[1], c = sp[2], d = sp[3];
    float h[HID] = {a.x, a.y, a.z, a.w, b.x, b.y, b.z, b.w,
                    c.x, c.y, c.z, c.w, d.x, d.y, d.z, d.w};
#pragma unroll
    for (int j = 0; j < HID; ++j) h[j] = fmaxf(fmaf(h[j], dv, b0[j]), 0.f);
    float o[NC];
#pragma unroll
    for (int c2 = 0; c2 < NC; ++c2) o[c2] = 0.f;
#pragma unroll
    for (int j = 0; j < HID; ++j)
#pragma unroll
        for (int c2 = 0; c2 < NC; ++c2)
            o[c2] = fmaf(h[j], W1[j * NC + c2], o[c2]);
#pragma unroll
    for (int c2 = 0; c2 < NC; ++c2)
        g1[(size_t)i * NC + c2] = o[c2] * dv;
}

__global__ void k_pull1(const int* __restrict__ rowptr, const int* __restrict__ esrc,
                        const float* __restrict__ g1, const float* __restrict__ dinv,
                        const float* __restrict__ b1, float* __restrict__ outp, int N) {
    int wid = (blockIdx.x * 256 + threadIdx.x) >> 6;
    if (wid >= N) return;
    int lane = threadIdx.x & 63;
    int grp = lane >> 3, j = lane & 7;
    int e0 = rowptr[wid], e1 = rowptr[wid + 1];
    float acc = 0.f;
    for (int base = e0; base < e1; base += 16) {
        int p = base + (lane & 15);
        int v = (p < e1) ? esrc[p] : 0;
#pragma unroll
        for (int u = 0; u < 2; ++u) {
            int k = grp + 8 * u;
            int idx = __shfl(v, k);
            if (base + k < e1 && j < NC) acc += g1[(size_t)idx * NC + j];
        }
    }
    acc += __shfl_xor(acc, 8);
    acc += __shfl_xor(acc, 16);
    acc += __shfl_xor(acc, 32);
    if (grp == 0 && j < NC)
        outp[(size_t)wid * NC + j] =
            fmaf(acc + g1[(size_t)wid * NC + j], dinv[wid], b1[j]);
}

// ---------------- launch ----------------

extern "C" void kernel_launch(void* const* d_in, const int* in_sizes, int n_in,
                              void* d_out, int out_size, void* d_ws, size_t ws_size,
                              hipStream_t stream) {
    const float* x  = (const float*)d_in[0];
    const int*   ei = (const int*)d_in[1];
    const float* W0 = (const float*)d_in[2];
    const float* b0 = (const float*)d_in[3];
    const float* W1 = (const float*)d_in[4];
    const float* b1 = (const float*)d_in[5];
    float* outp = (float*)d_out;

    int N = in_sizes[0] / FIN;
    int E = in_sizes[1] / 2;
    const int* src = ei;
    const int* dst = ei + E;

    float* fws = (float*)d_ws;
    float* g0   = fws;                       // t0 then scaled in place
    float* s0   = fws + (size_t)16 * N;
    float* g1   = fws + (size_t)32 * N;
    float* dinv = fws + (size_t)39 * N;
    int* iws    = (int*)(fws + (size_t)40 * N);
    int* rowptr = iws;                       // N+1
    int* cursor = iws + (N + 1);             // N
    int* cnt    = iws + (2 * N + 1);         // N
    int* bsum   = iws + (3 * N + 1);         // 1024
    int* boff   = iws + (3 * N + 1 + 1024);  // 1024
    int* esrc   = iws + (3 * N + 1 + 2048);  // E

    int nb  = (N + 255) / 256;
    int nbx = (N + 63) / 64;        // xw0 blocks
    int nbh = (E + 255) / 256;      // hist blocks
    int nbf = (E + 255) / 256;      // fill blocks
    int n4  = 4 * N;                // float4 count of g0
    int nbs = (n4 + 255) / 256;     // scale blocks

    hipMemsetAsync(cnt, 0, (size_t)N * sizeof(int), stream);

    k_xw0_hist<<<nbx + nbh, 256, 0, stream>>>(x, W0, g0, N, nbx, dst, cnt, E);

    k_bsum<<<nb, 256, 0, stream>>>(cnt, bsum, N);
    k_scanb<<<1, 1024, 0, stream>>>(bsum, boff, nb);
    k_rowptr<<<(N + 1 + 255) / 256, 256, 0, stream>>>(cnt, boff, rowptr, cursor, dinv, N, E);

    k_fill_scale<<<nbf + nbs, 256, 0, stream>>>(src, dst, cursor, esrc, E,
                                                nbf, (float4*)g0, dinv, n4);

    k_pull0<<<(int)(((size_t)N * 64 + 255) / 256), 256, 0, stream>>>(rowptr, esrc, g0, s0, N);
    k_h1w1<<<nb, 256, 0, stream>>>(s0, dinv, b0, W1, g1, N);
    k_pull1<<<(int)(((size_t)N * 64 + 255) / 256), 256, 0, stream>>>(rowptr, esrc, g1, dinv, b1, outp, N);
}

// Round 11
// 346.858 us; speedup vs baseline: 1.1081x; 1.1081x over previous
//
#include <hip/hip_runtime.h>
#include <stdint.h>

constexpr int FIN = 512;
constexpr int HID = 16;
constexpr int NC  = 7;

typedef const __attribute__((address_space(1))) void* gas_ptr;
typedef __attribute__((address_space(3))) void* las_ptr;

// ---------------- CSR build ----------------

__global__ void k_bsum(const int* __restrict__ cnt, int* __restrict__ bsum, int N) {
    int i = blockIdx.x * 256 + threadIdx.x;
    int v = (i < N) ? cnt[i] : 0;
#pragma unroll
    for (int o = 1; o < 64; o <<= 1) v += __shfl_xor(v, o);
    __shared__ int ws_[4];
    if ((threadIdx.x & 63) == 0) ws_[threadIdx.x >> 6] = v;
    __syncthreads();
    if (threadIdx.x == 0) bsum[blockIdx.x] = ws_[0] + ws_[1] + ws_[2] + ws_[3];
}

__global__ void k_scanb(const int* __restrict__ bsum, int* __restrict__ boff, int nb) {
    __shared__ int s[1024];
    int t = threadIdx.x;
    int mine = (t < nb) ? bsum[t] : 0;
    s[t] = mine;
    __syncthreads();
    for (int o = 1; o < 1024; o <<= 1) {
        int v = (t >= o) ? s[t - o] : 0;
        __syncthreads();
        s[t] += v;
        __syncthreads();
    }
    if (t < nb) boff[t] = s[t] - mine;  // exclusive
}

__global__ void k_rowptr(const int* __restrict__ cnt, const int* __restrict__ boff,
                         int* __restrict__ rowptr, int* __restrict__ cursor,
                         float* __restrict__ dinv, int N, int E) {
    int i = blockIdx.x * 256 + threadIdx.x;
    int v = (i < N) ? cnt[i] : 0;
    int lane = threadIdx.x & 63, w = threadIdx.x >> 6;
    int xs = v;
#pragma unroll
    for (int o = 1; o < 64; o <<= 1) {
        int y = __shfl_up(xs, o);
        if (lane >= o) xs += y;
    }
    __shared__ int wsum[4];
    if (lane == 63) wsum[w] = xs;
    __syncthreads();
    int woff = 0;
    for (int k = 0; k < w; ++k) woff += wsum[k];
    if (i < N) {
        int rp = boff[blockIdx.x] + woff + xs - v;
        rowptr[i] = rp;
        cursor[i] = rp;
        dinv[i] = rsqrtf((float)v + 1.0f);
    }
    if (i == N) rowptr[N] = E;
}

// ---------------- layer 0 transform: t0 = x @ W0 (unscaled) + hist tail ------
// 8-row tiles (16KB). Staging: global_load_lds, each instr covers one 1KB
// half-row span (per-lane source pre-swizzled within the span), tiles walked
// sequentially per block -> prefetch-friendly. Compute-side ds_read_b128 is
// conflict-free per 8-lane group (slot%8 = kd^r bijective in r). 2 buffers,
// stage-ahead-2, exact counted vmcnt (order pinned by sched_barrier between
// stage-issue and store); raw s_barrier with lgkmcnt-only drains so
// prefetched loads survive barriers.

__global__ void __launch_bounds__(256, 2) k_xw0(
    const float* __restrict__ x, const float* __restrict__ W0,
    float* __restrict__ t0g, int N, int nbx,
    const int* __restrict__ dst, int* __restrict__ cnt, int E) {
    __shared__ float lds[16896];        // bufs 2x4096 | W 8192 | red 512
    float* Wl  = lds + 8192;
    float* red = lds + 16384;

    const int tid  = threadIdx.x;
    const int w    = tid >> 6;
    const int lane = tid & 63;
    const int kd   = lane >> 3;         // 0..7  k-dup slot
    const int r    = lane & 7;          // 0..7  row slot
    const bool storer = (tid < 128);
    const int bid = blockIdx.x;

    int ntiles = (N + 7) / 8;
    int t0 = (int)((size_t)bid * ntiles / nbx);
    int t1 = (int)((size_t)(bid + 1) * ntiles / nbx);

    // stage tile's 8 rows: 16 instrs x 1KB span (4 per wave)
    auto STAGE = [&](float* buf, int tile) {
#pragma unroll
        for (int i = 0; i < 4; ++i) {
            int hr = w * 4 + i;                 // half-row 0..15
            int row = hr >> 1, half = hr & 1;
            int srcSlot = half * 64 + (lane ^ row);  // pre-swizzled source slot
            int grow = tile * 8 + row;
            if (grow >= N) grow = N - 1;
            const float* gp = x + (size_t)grow * FIN + srcSlot * 4;
            __builtin_amdgcn_global_load_lds(
                (gas_ptr)gp, (las_ptr)((char*)buf + hr * 1024 + lane * 16), 16, 0, 0);
        }
    };

    if (t1 - t0 >= 1) STAGE(lds, t0);
    if (t1 - t0 >= 2) STAGE(lds + 4096, t0 + 1);

    // W -> LDS, swizzled: phys jq' = jq ^ ((k>>2)&3)
#pragma unroll
    for (int s = 0; s < 8; ++s) {
        int f = s * 256 + tid;              // 16B-slot id, 0..2047
        int k = f >> 2, jq = f & 3;
        int jqp = jq ^ ((k >> 2) & 3);
        float4 v = *(const float4*)(W0 + f * 4);
        *(float4*)(Wl + (size_t)(k * 4 + jqp) * 4) = v;
    }
    __syncthreads();   // full drain once (stages t0,t0+1 complete under W-copy)

    const bool tiny = (t1 - t0 < 4);
    for (int t = t0; t < t1; ++t) {
        int li = t - t0;                       // local tile index (parity base)
        float* buf = (li & 1) ? (lds + 4096) : lds;

        // A: my stage(t) landed (exact per-wave op accounting; order pinned)
        int K;
        if (tiny || t == t0)  K = tiny ? 0 : 4;
        else if (t == t1 - 1) K = storer ? 2 : 0;
        else if (t == t0 + 1) K = storer ? 5 : 4;
        else                  K = storer ? 6 : 4;
        if (K == 0)      asm volatile("s_waitcnt vmcnt(0)" ::: "memory");
        else if (K == 2) asm volatile("s_waitcnt vmcnt(2)" ::: "memory");
        else if (K == 4) asm volatile("s_waitcnt vmcnt(4)" ::: "memory");
        else if (K == 5) asm volatile("s_waitcnt vmcnt(5)" ::: "memory");
        else             asm volatile("s_waitcnt vmcnt(6)" ::: "memory");
        __builtin_amdgcn_sched_barrier(0);
        __builtin_amdgcn_s_barrier();       // all waves' stage(t) done
        __builtin_amdgcn_sched_barrier(0);

        // B: compute partials (k-split by wave; kd-split in-lane)
        float acc[16];
#pragma unroll
        for (int j = 0; j < 16; ++j) acc[j] = 0.f;
#pragma unroll
        for (int g4 = 0; g4 < 4; ++g4) {
            int gbase = w * 32 + g4 * 8;
            float4 xv = *(const float4*)(buf + r * 512 + (gbase + (kd ^ r)) * 4);
            int k0 = (gbase + kd) * 4;
#pragma unroll
            for (int e = 0; e < 4; ++e) {
                float xe = (&xv.x)[e];
                int k = k0 + e;
#pragma unroll
                for (int jq = 0; jq < 4; ++jq) {
                    int jqp = jq ^ (kd & 3);
                    float4 wv = *(const float4*)(Wl + (size_t)(k * 16 + jqp * 4));
                    acc[jq * 4 + 0] = fmaf(xe, wv.x, acc[jq * 4 + 0]);
                    acc[jq * 4 + 1] = fmaf(xe, wv.y, acc[jq * 4 + 1]);
                    acc[jq * 4 + 2] = fmaf(xe, wv.z, acc[jq * 4 + 2]);
                    acc[jq * 4 + 3] = fmaf(xe, wv.w, acc[jq * 4 + 3]);
                }
            }
        }

        // C: reduce over kd (lane bits 3,4,5), then stash per-wave row sums
#pragma unroll
        for (int j = 0; j < 16; ++j) acc[j] += __shfl_xor(acc[j], 8);
#pragma unroll
        for (int j = 0; j < 16; ++j) acc[j] += __shfl_xor(acc[j], 16);
#pragma unroll
        for (int j = 0; j < 16; ++j) acc[j] += __shfl_xor(acc[j], 32);
        if (kd == 0) {
            float* rp = red + (w * 8 + r) * 16;
#pragma unroll
            for (int q = 0; q < 4; ++q) {
                float4 v;
                v.x = acc[q * 4 + 0]; v.y = acc[q * 4 + 1];
                v.z = acc[q * 4 + 2]; v.w = acc[q * 4 + 3];
                *(float4*)(rp + q * 4) = v;
            }
        }
        asm volatile("s_waitcnt lgkmcnt(0)" ::: "memory");  // ds drained, NOT vmem
        __builtin_amdgcn_sched_barrier(0);
        __builtin_amdgcn_s_barrier();       // red ready; buf free
        __builtin_amdgcn_sched_barrier(0);

        // D: stage tile t+2 into the freed buffer (same parity as t)
        if (t + 2 < t1) STAGE(buf, t + 2);
        __builtin_amdgcn_sched_barrier(0);  // pin: stage loads BEFORE store

        // E: cross-wave reduce + coalesced store (waves 0,1 only)
        if (storer) {
            float s = red[tid] + red[128 + tid] + red[256 + tid] + red[384 + tid];
            int row = t * 8 + (tid >> 4);
            if (row < N) t0g[(size_t)t * 128 + tid] = s;
        }
    }

    // hist tail: this block's slice of edges
    size_t e0 = (size_t)bid * E / nbx, e1 = (size_t)(bid + 1) * E / nbx;
    for (size_t e = e0 + tid; e < e1; e += 256)
        atomicAdd(&cnt[dst[e]], 1);
}

// ---------------- fused: CSR fill + g0 *= dinv (in place) ----------------

__global__ void k_fill_scale(const int* __restrict__ src, const int* __restrict__ dst,
                             int* __restrict__ cursor, int* __restrict__ esrc, int E,
                             int nbf, float4* __restrict__ g4,
                             const float* __restrict__ dinv, int n4) {
    if ((int)blockIdx.x < nbf) {  // -------- fill blocks --------
        int e = blockIdx.x * 256 + threadIdx.x;
        if (e < E) {
            int p = atomicAdd(&cursor[dst[e]], 1);
            esrc[p] = src[e];
        }
        return;
    }
    int t = (blockIdx.x - nbf) * 256 + threadIdx.x;  // -------- scale blocks --------
    if (t < n4) {
        float dv = dinv[t >> 2];
        float4 v = g4[t];
        v.x *= dv; v.y *= dv; v.z *= dv; v.w *= dv;
        g4[t] = v;
    }
}

// ---------------- pull aggregation (wave per dst row, batched gathers) -------

__global__ void k_pull0(const int* __restrict__ rowptr, const int* __restrict__ esrc,
                        const float* __restrict__ g0, float* __restrict__ s0, int N) {
    int wid = (blockIdx.x * 256 + threadIdx.x) >> 6;
    if (wid >= N) return;
    int lane = threadIdx.x & 63;
    int grp = lane >> 4, j = lane & 15;
    int e0 = rowptr[wid], e1 = rowptr[wid + 1];
    float acc = 0.f;
    for (int base = e0; base < e1; base += 16) {
        int p = base + (lane & 15);
        int v = (p < e1) ? esrc[p] : 0;
#pragma unroll
        for (int u = 0; u < 4; ++u) {
            int k = grp + 4 * u;
            int idx = __shfl(v, k);
            if (base + k < e1) acc += g0[(size_t)idx * HID + j];
        }
    }
    acc += __shfl_xor(acc, 16);
    acc += __shfl_xor(acc, 32);
    if (grp == 0)
        s0[(size_t)wid * HID + j] = acc + g0[(size_t)wid * HID + j];
}

__global__ void k_h1w1(const float* __restrict__ s0, const float* __restrict__ dinv,
                       const float* __restrict__ b0, const float* __restrict__ W1,
                       float* __restrict__ g1, int N) {
    int i = blockIdx.x * 256 + threadIdx.x;
    if (i >= N) return;
    float dv = dinv[i];
    const float4* sp = (const float4*)(s0 + (size_t)i * HID);
    float4 a = sp[0], b = sp[1], c = sp[2], d = sp[3];
    float h[HID] = {a.x, a.y, a.z, a.w, b.x, b.y, b.z, b.w,
                    c.x, c.y, c.z, c.w, d.x, d.y, d.z, d.w};
#pragma unroll
    for (int j = 0; j < HID; ++j) h[j] = fmaxf(fmaf(h[j], dv, b0[j]), 0.f);
    float o[NC];
#pragma unroll
    for (int c2 = 0; c2 < NC; ++c2) o[c2] = 0.f;
#pragma unroll
    for (int j = 0; j < HID; ++j)
#pragma unroll
        for (int c2 = 0; c2 < NC; ++c2)
            o[c2] = fmaf(h[j], W1[j * NC + c2], o[c2]);
#pragma unroll
    for (int c2 = 0; c2 < NC; ++c2)
        g1[(size_t)i * NC + c2] = o[c2] * dv;
}

__global__ void k_pull1(const int* __restrict__ rowptr, const int* __restrict__ esrc,
                        const float* __restrict__ g1, const float* __restrict__ dinv,
                        const float* __restrict__ b1, float* __restrict__ outp, int N) {
    int wid = (blockIdx.x * 256 + threadIdx.x) >> 6;
    if (wid >= N) return;
    int lane = threadIdx.x & 63;
    int grp = lane >> 3, j = lane & 7;
    int e0 = rowptr[wid], e1 = rowptr[wid + 1];
    float acc = 0.f;
    for (int base = e0; base < e1; base += 16) {
        int p = base + (lane & 15);
        int v = (p < e1) ? esrc[p] : 0;
#pragma unroll
        for (int u = 0; u < 2; ++u) {
            int k = grp + 8 * u;
            int idx = __shfl(v, k);
            if (base + k < e1 && j < NC) acc += g1[(size_t)idx * NC + j];
        }
    }
    acc += __shfl_xor(acc, 8);
    acc += __shfl_xor(acc, 16);
    acc += __shfl_xor(acc, 32);
    if (grp == 0 && j < NC)
        outp[(size_t)wid * NC + j] =
            fmaf(acc + g1[(size_t)wid * NC + j], dinv[wid], b1[j]);
}

// ---------------- launch ----------------

extern "C" void kernel_launch(void* const* d_in, const int* in_sizes, int n_in,
                              void* d_out, int out_size, void* d_ws, size_t ws_size,
                              hipStream_t stream) {
    const float* x  = (const float*)d_in[0];
    const int*   ei = (const int*)d_in[1];
    const float* W0 = (const float*)d_in[2];
    const float* b0 = (const float*)d_in[3];
    const float* W1 = (const float*)d_in[4];
    const float* b1 = (const float*)d_in[5];
    float* outp = (float*)d_out;

    int N = in_sizes[0] / FIN;
    int E = in_sizes[1] / 2;
    const int* src = ei;
    const int* dst = ei + E;

    float* fws = (float*)d_ws;
    float* g0   = fws;                       // t0 then scaled in place
    float* s0   = fws + (size_t)16 * N;
    float* g1   = fws + (size_t)32 * N;
    float* dinv = fws + (size_t)39 * N;
    int* iws    = (int*)(fws + (size_t)40 * N);
    int* rowptr = iws;                       // N+1
    int* cursor = iws + (N + 1);             // N
    int* cnt    = iws + (2 * N + 1);         // N
    int* bsum   = iws + (3 * N + 1);         // 1024
    int* boff   = iws + (3 * N + 1 + 1024);  // 1024
    int* esrc   = iws + (3 * N + 1 + 2048);  // E

    int nb  = (N + 255) / 256;
    int ntiles = (N + 7) / 8;
    int nbx = 512;
    if (ntiles / 2 < nbx) nbx = (ntiles / 2 > 0) ? ntiles / 2 : 1;
    int nbf = (E + 255) / 256;      // fill blocks
    int n4  = 4 * N;                // float4 count of g0
    int nbs = (n4 + 255) / 256;     // scale blocks

    hipMemsetAsync(cnt, 0, (size_t)N * sizeof(int), stream);

    k_xw0<<<nbx, 256, 0, stream>>>(x, W0, g0, N, nbx, dst, cnt, E);

    k_bsum<<<nb, 256, 0, stream>>>(cnt, bsum, N);
    k_scanb<<<1, 1024, 0, stream>>>(bsum, boff, nb);
    k_rowptr<<<(N + 1 + 255) / 256, 256, 0, stream>>>(cnt, boff, rowptr, cursor, dinv, N, E);

    k_fill_scale<<<nbf + nbs, 256, 0, stream>>>(src, dst, cursor, esrc, E,
                                                nbf, (float4*)g0, dinv, n4);

    k_pull0<<<(int)(((size_t)N * 64 + 255) / 256), 256, 0, stream>>>(rowptr, esrc, g0, s0, N);
    k_h1w1<<<nb, 256, 0, stream>>>(s0, dinv, b0, W1, g1, N);
    k_pull1<<<(int)(((size_t)N * 64 + 255) / 256), 256, 0, stream>>>(rowptr, esrc, g1, dinv, b1, outp, N);
}

// Round 12
// 342.938 us; speedup vs baseline: 1.1207x; 1.0114x over previous
//
#include <hip/hip_runtime.h>
#include <stdint.h>

constexpr int FIN = 512;
constexpr int HID = 16;
constexpr int NC  = 7;

typedef const __attribute__((address_space(1))) void* gas_ptr;
typedef __attribute__((address_space(3))) void* las_ptr;

// ---------------- CSR build ----------------

__global__ void k_bsum(const int* __restrict__ cnt, int* __restrict__ bsum, int N) {
    int i = blockIdx.x * 256 + threadIdx.x;
    int v = (i < N) ? cnt[i] : 0;
#pragma unroll
    for (int o = 1; o < 64; o <<= 1) v += __shfl_xor(v, o);
    __shared__ int ws_[4];
    if ((threadIdx.x & 63) == 0) ws_[threadIdx.x >> 6] = v;
    __syncthreads();
    if (threadIdx.x == 0) bsum[blockIdx.x] = ws_[0] + ws_[1] + ws_[2] + ws_[3];
}

__global__ void k_scanb(const int* __restrict__ bsum, int* __restrict__ boff, int nb) {
    __shared__ int s[1024];
    int t = threadIdx.x;
    int mine = (t < nb) ? bsum[t] : 0;
    s[t] = mine;
    __syncthreads();
    for (int o = 1; o < 1024; o <<= 1) {
        int v = (t >= o) ? s[t - o] : 0;
        __syncthreads();
        s[t] += v;
        __syncthreads();
    }
    if (t < nb) boff[t] = s[t] - mine;  // exclusive
}

__global__ void k_rowptr(const int* __restrict__ cnt, const int* __restrict__ boff,
                         int* __restrict__ rowptr, int* __restrict__ cursor,
                         float* __restrict__ dinv, int N, int E) {
    int i = blockIdx.x * 256 + threadIdx.x;
    int v = (i < N) ? cnt[i] : 0;
    int lane = threadIdx.x & 63, w = threadIdx.x >> 6;
    int xs = v;
#pragma unroll
    for (int o = 1; o < 64; o <<= 1) {
        int y = __shfl_up(xs, o);
        if (lane >= o) xs += y;
    }
    __shared__ int wsum[4];
    if (lane == 63) wsum[w] = xs;
    __syncthreads();
    int woff = 0;
    for (int k = 0; k < w; ++k) woff += wsum[k];
    if (i < N) {
        int rp = boff[blockIdx.x] + woff + xs - v;
        rowptr[i] = rp;
        cursor[i] = rp;
        dinv[i] = rsqrtf((float)v + 1.0f);
    }
    if (i == N) rowptr[N] = E;
}

// ---------------- layer 0 transform: t0 = x @ W0 (unscaled) + hist tail ------
// One wave per block; wave owns 64 rows + private 16KB LDS ring (4 x 4KB
// chunks of 64 rows x 16 cols). Stage via global_load_lds: each instr = 16
// rows x 64B = 16 fully-covered lines (true coalescing). LDS layout
// phys16Bslot = (r>>3)*32 + s*8 + (r&7): coalesced staging AND even-spread
// compute reads. Compute: row-per-lane, W via wave-uniform s_load (no W in
// LDS), acc[16] persistent. ZERO barriers; per-wave counted vmcnt (stage ops
// are the only vmem in the loop; W s_loads are lgkm). Stage-ahead-3.

__global__ void __launch_bounds__(64) k_xw0(
    const float* __restrict__ x, const float* __restrict__ W0,
    float* __restrict__ t0g, int N, int nbx,
    const int* __restrict__ dst, int* __restrict__ cnt, int E) {
    __shared__ float ring[4096];        // 4 x 1024 floats (4KB chunks)

    const int l   = threadIdx.x;        // lane 0..63
    const int bid = blockIdx.x;
    const int row0 = bid * 64;

    // stage chunk c into ring slot (c&3): 4 instrs, each 16 rows x 64B
    auto STAGE = [&](int c) {
        float* buf = ring + (c & 3) * 1024;
#pragma unroll
        for (int i = 0; i < 4; ++i) {
            int row = i * 16 + (l >> 5) * 8 + (l & 7);  // row within block
            int s = (l >> 3) & 3;                        // 16B slot within 64B
            int grow = row0 + row;
            if (grow >= N) grow = N - 1;
            const float* gp = x + (size_t)grow * FIN + c * 16 + s * 4;
            __builtin_amdgcn_global_load_lds(
                (gas_ptr)gp, (las_ptr)((char*)buf + i * 1024 + l * 16), 16, 0, 0);
        }
    };

    float acc[HID];
#pragma unroll
    for (int j = 0; j < HID; ++j) acc[j] = 0.f;

    STAGE(0); STAGE(1); STAGE(2);       // 12 loads in flight

    const int r = l;                     // compute lane owns row r
    for (int c = 0; c < 32; ++c) {
        // wait: chunk c's 4 loads landed (per-wave counter; no barrier needed)
        if (c <= 29)      asm volatile("s_waitcnt vmcnt(8)" ::: "memory");
        else if (c == 30) asm volatile("s_waitcnt vmcnt(4)" ::: "memory");
        else              asm volatile("s_waitcnt vmcnt(0)" ::: "memory");
        __builtin_amdgcn_sched_barrier(0);

        const float* buf = ring + (c & 3) * 1024;
        float4 xq[4];
#pragma unroll
        for (int s = 0; s < 4; ++s) {
            int idx = (r >> 3) * 32 + s * 8 + (r & 7);   // 16B slot
            xq[s] = *(const float4*)(buf + idx * 4);
        }

        if (c + 3 < 32) STAGE(c + 3);    // refill freed ring slot

        const float* wc = W0 + (size_t)c * 16 * HID;     // uniform -> s_load
#pragma unroll
        for (int s = 0; s < 4; ++s) {
            const float* wk = wc + s * 4 * HID;
#pragma unroll
            for (int e = 0; e < 4; ++e) {
                float xe = (&xq[s].x)[e];
#pragma unroll
                for (int j = 0; j < HID; ++j)
                    acc[j] = fmaf(xe, wk[e * HID + j], acc[j]);
            }
        }
    }

    int row = row0 + r;
    if (row < N) {
        float4* gp = (float4*)(t0g + (size_t)row * HID);
#pragma unroll
        for (int q = 0; q < 4; ++q) {
            float4 v;
            v.x = acc[q * 4 + 0]; v.y = acc[q * 4 + 1];
            v.z = acc[q * 4 + 2]; v.w = acc[q * 4 + 3];
            gp[q] = v;
        }
    }

    // hist tail: this block's slice of edges
    size_t e0 = (size_t)bid * E / nbx, e1 = (size_t)(bid + 1) * E / nbx;
    for (size_t e = e0 + l; e < e1; e += 64)
        atomicAdd(&cnt[dst[e]], 1);
}

// ---------------- fused: CSR fill + g0 *= dinv (in place) ----------------

__global__ void k_fill_scale(const int* __restrict__ src, const int* __restrict__ dst,
                             int* __restrict__ cursor, int* __restrict__ esrc, int E,
                             int nbf, float4* __restrict__ g4,
                             const float* __restrict__ dinv, int n4) {
    if ((int)blockIdx.x < nbf) {  // -------- fill blocks --------
        int e = blockIdx.x * 256 + threadIdx.x;
        if (e < E) {
            int p = atomicAdd(&cursor[dst[e]], 1);
            esrc[p] = src[e];
        }
        return;
    }
    int t = (blockIdx.x - nbf) * 256 + threadIdx.x;  // -------- scale blocks --------
    if (t < n4) {
        float dv = dinv[t >> 2];
        float4 v = g4[t];
        v.x *= dv; v.y *= dv; v.z *= dv; v.w *= dv;
        g4[t] = v;
    }
}

// ---------------- pull aggregation (wave per dst row, batched gathers) -------

__global__ void k_pull0(const int* __restrict__ rowptr, const int* __restrict__ esrc,
                        const float* __restrict__ g0, float* __restrict__ s0, int N) {
    int wid = (blockIdx.x * 256 + threadIdx.x) >> 6;
    if (wid >= N) return;
    int lane = threadIdx.x & 63;
    int grp = lane >> 4, j = lane & 15;
    int e0 = rowptr[wid], e1 = rowptr[wid + 1];
    float acc = 0.f;
    for (int base = e0; base < e1; base += 16) {
        int p = base + (lane & 15);
        int v = (p < e1) ? esrc[p] : 0;
#pragma unroll
        for (int u = 0; u < 4; ++u) {
            int k = grp + 4 * u;
            int idx = __shfl(v, k);
            if (base + k < e1) acc += g0[(size_t)idx * HID + j];
        }
    }
    acc += __shfl_xor(acc, 16);
    acc += __shfl_xor(acc, 32);
    if (grp == 0)
        s0[(size_t)wid * HID + j] = acc + g0[(size_t)wid * HID + j];
}

__global__ void k_h1w1(const float* __restrict__ s0, const float* __restrict__ dinv,
                       const float* __restrict__ b0, const float* __restrict__ W1,
                       float* __restrict__ g1, int N) {
    int i = blockIdx.x * 256 + threadIdx.x;
    if (i >= N) return;
    float dv = dinv[i];
    const float4* sp = (const float4*)(s0 + (size_t)i * HID);
    float4 a = sp[0], b = sp[1], c = sp[2], d = sp[3];
    float h[HID] = {a.x, a.y, a.z, a.w, b.x, b.y, b.z, b.w,
                    c.x, c.y, c.z, c.w, d.x, d.y, d.z, d.w};
#pragma unroll
    for (int j = 0; j < HID; ++j) h[j] = fmaxf(fmaf(h[j], dv, b0[j]), 0.f);
    float o[NC];
#pragma unroll
    for (int c2 = 0; c2 < NC; ++c2) o[c2] = 0.f;
#pragma unroll
    for (int j = 0; j < HID; ++j)
#pragma unroll
        for (int c2 = 0; c2 < NC; ++c2)
            o[c2] = fmaf(h[j], W1[j * NC + c2], o[c2]);
#pragma unroll
    for (int c2 = 0; c2 < NC; ++c2)
        g1[(size_t)i * NC + c2] = o[c2] * dv;
}

__global__ void k_pull1(const int* __restrict__ rowptr, const int* __restrict__ esrc,
                        const float* __restrict__ g1, const float* __restrict__ dinv,
                        const float* __restrict__ b1, float* __restrict__ outp, int N) {
    int wid = (blockIdx.x * 256 + threadIdx.x) >> 6;
    if (wid >= N) return;
    int lane = threadIdx.x & 63;
    int grp = lane >> 3, j = lane & 7;
    int e0 = rowptr[wid], e1 = rowptr[wid + 1];
    float acc = 0.f;
    for (int base = e0; base < e1; base += 16) {
        int p = base + (lane & 15);
        int v = (p < e1) ? esrc[p] : 0;
#pragma unroll
        for (int u = 0; u < 2; ++u) {
            int k = grp + 8 * u;
            int idx = __shfl(v, k);
            if (base + k < e1 && j < NC) acc += g1[(size_t)idx * NC + j];
        }
    }
    acc += __shfl_xor(acc, 8);
    acc += __shfl_xor(acc, 16);
    acc += __shfl_xor(acc, 32);
    if (grp == 0 && j < NC)
        outp[(size_t)wid * NC + j] =
            fmaf(acc + g1[(size_t)wid * NC + j], dinv[wid], b1[j]);
}

// ---------------- launch ----------------

extern "C" void kernel_launch(void* const* d_in, const int* in_sizes, int n_in,
                              void* d_out, int out_size, void* d_ws, size_t ws_size,
                              hipStream_t stream) {
    const float* x  = (const float*)d_in[0];
    const int*   ei = (const int*)d_in[1];
    const float* W0 = (const float*)d_in[2];
    const float* b0 = (const float*)d_in[3];
    const float* W1 = (const float*)d_in[4];
    const float* b1 = (const float*)d_in[5];
    float* outp = (float*)d_out;

    int N = in_sizes[0] / FIN;
    int E = in_sizes[1] / 2;
    const int* src = ei;
    const int* dst = ei + E;

    float* fws = (float*)d_ws;
    float* g0   = fws;                       // t0 then scaled in place
    float* s0   = fws + (size_t)16 * N;
    float* g1   = fws + (size_t)32 * N;
    float* dinv = fws + (size_t)39 * N;
    int* iws    = (int*)(fws + (size_t)40 * N);
    int* rowptr = iws;                       // N+1
    int* cursor = iws + (N + 1);             // N
    int* cnt    = iws + (2 * N + 1);         // N
    int* bsum   = iws + (3 * N + 1);         // 1024
    int* boff   = iws + (3 * N + 1 + 1024);  // 1024
    int* esrc   = iws + (3 * N + 1 + 2048);  // E

    int nb  = (N + 255) / 256;
    int nbx = (N + 63) / 64;        // xw0 blocks (1 wave each)
    int nbf = (E + 255) / 256;      // fill blocks
    int n4  = 4 * N;                // float4 count of g0
    int nbs = (n4 + 255) / 256;     // scale blocks

    hipMemsetAsync(cnt, 0, (size_t)N * sizeof(int), stream);

    k_xw0<<<nbx, 64, 0, stream>>>(x, W0, g0, N, nbx, dst, cnt, E);

    k_bsum<<<nb, 256, 0, stream>>>(cnt, bsum, N);
    k_scanb<<<1, 1024, 0, stream>>>(bsum, boff, nb);
    k_rowptr<<<(N + 1 + 255) / 256, 256, 0, stream>>>(cnt, boff, rowptr, cursor, dinv, N, E);

    k_fill_scale<<<nbf + nbs, 256, 0, stream>>>(src, dst, cursor, esrc, E,
                                                nbf, (float4*)g0, dinv, n4);

    k_pull0<<<(int)(((size_t)N * 64 + 255) / 256), 256, 0, stream>>>(rowptr, esrc, g0, s0, N);
    k_h1w1<<<nb, 256, 0, stream>>>(s0, dinv, b0, W1, g1, N);
    k_pull1<<<(int)(((size_t)N * 64 + 255) / 256), 256, 0, stream>>>(rowptr, esrc, g1, dinv, b1, outp, N);
}